// Round 1
// baseline (149.906 us; speedup 1.0000x reference)
//
#include <hip/hip_runtime.h>
#include <hip/hip_bf16.h>
#include <cstdint>

#define B_ 8
#define N_ 512
#define D_ 256
#define E_ 16384
#define K_ 512   // 2*D
#define H_ 256   // hidden dim

#define BK 32
#define SA_STRIDE 56   // bf16 elems -> 112 B row stride: 16B aligned, 2-way bank (free)
#define SB_STRIDE 56

using bf16x8 = __attribute__((ext_vector_type(8))) short;
using f32x4  = __attribute__((ext_vector_type(4))) float;

__device__ inline unsigned short f2bf(float f) {
    union { float f; unsigned u; } v; v.f = f;
    unsigned u = v.u;
    return (unsigned short)((u + 0x7fffu + ((u >> 16) & 1u)) >> 16);  // RNE
}

__global__ void zero_out_k(float4* __restrict__ out, int n4) {
    int i = blockIdx.x * blockDim.x + threadIdx.x;
    if (i < n4) out[i] = make_float4(0.f, 0.f, 0.f, 0.f);
}

// W1 (512,256) fp32 row-major -> W1T (256,512) bf16 row-major
__global__ void conv_w1t_k(const float* __restrict__ W1, unsigned short* __restrict__ W1T) {
    int i = blockIdx.x * 256 + threadIdx.x;      // 0..131071
    int k = i >> 8, n = i & 255;
    W1T[n * K_ + k] = f2bf(W1[i]);
}

__global__ __launch_bounds__(256)
void fused_edge_mlp(const float* __restrict__ feat,          // (B,N,D) fp32
                    const unsigned short* __restrict__ W1T,  // (H,K) bf16
                    const float* __restrict__ b1,            // (H)
                    const float* __restrict__ W2,            // (H,1)
                    const float* __restrict__ b2,            // (1)
                    const int* __restrict__ eidx,            // (2,E) int32
                    float* __restrict__ out)                 // (B,N,N)
{
    __shared__ unsigned short sA[64 * SA_STRIDE];
    __shared__ unsigned short sB[H_ * SB_STRIDE];
    __shared__ int sSrc[64], sDst[64];
    __shared__ float sS[4][64];

    const int t      = threadIdx.x;
    const int m_base = blockIdx.x * 64;
    const int b      = m_base >> 14;          // / E_
    const int e_base = m_base & (E_ - 1);

    if (t < 64) {
        sSrc[t] = eidx[e_base + t];
        sDst[t] = eidx[E_ + e_base + t];
    }
    __syncthreads();

    // A staging assignment: 4 threads per row, 8 k-elems each
    const int arow = t >> 2;
    const int akg  = (t & 3) * 8;
    const float* featB = feat + (size_t)b * N_ * D_;
    const float* pSrc  = featB + sSrc[arow] * D_;
    const float* pDst  = featB + sDst[arow] * D_;

    const int wave = t >> 6;
    const int lane = t & 63;
    const int l15  = lane & 15;
    const int quad = lane >> 4;

    f32x4 acc[4][4];
#pragma unroll
    for (int rm = 0; rm < 4; rm++)
#pragma unroll
        for (int cn = 0; cn < 4; cn++)
            acc[rm][cn] = (f32x4){0.f, 0.f, 0.f, 0.f};

    for (int k0 = 0; k0 < K_; k0 += BK) {
        __syncthreads();
        // ---- stage A: gather + fp32->bf16 convert ----
        {
            int kk = k0 + akg;
            const float* p = (kk < D_) ? (pSrc + kk) : (pDst + (kk - D_));
            float4 lo = *(const float4*)p;
            float4 hi = *(const float4*)(p + 4);
            union { bf16x8 v; unsigned short s[8]; } u;
            u.s[0] = f2bf(lo.x); u.s[1] = f2bf(lo.y); u.s[2] = f2bf(lo.z); u.s[3] = f2bf(lo.w);
            u.s[4] = f2bf(hi.x); u.s[5] = f2bf(hi.y); u.s[6] = f2bf(hi.z); u.s[7] = f2bf(hi.w);
            *(bf16x8*)(sA + arow * SA_STRIDE + akg) = u.v;
        }
        // ---- stage B: W1T tile, thread t owns h-row t ----
        {
            const unsigned short* p = W1T + (size_t)t * K_ + k0;
            uint4 q0 = *(const uint4*)(p);
            uint4 q1 = *(const uint4*)(p + 8);
            uint4 q2 = *(const uint4*)(p + 16);
            uint4 q3 = *(const uint4*)(p + 24);
            *(uint4*)(sB + t * SB_STRIDE +  0) = q0;
            *(uint4*)(sB + t * SB_STRIDE +  8) = q1;
            *(uint4*)(sB + t * SB_STRIDE + 16) = q2;
            *(uint4*)(sB + t * SB_STRIDE + 24) = q3;
        }
        __syncthreads();

        bf16x8 af[4], bfr[4];
#pragma unroll
        for (int rm = 0; rm < 4; rm++)
            af[rm] = *(const bf16x8*)(sA + (rm * 16 + l15) * SA_STRIDE + quad * 8);
#pragma unroll
        for (int cn = 0; cn < 4; cn++)
            bfr[cn] = *(const bf16x8*)(sB + (wave * 64 + cn * 16 + l15) * SB_STRIDE + quad * 8);
#pragma unroll
        for (int rm = 0; rm < 4; rm++)
#pragma unroll
            for (int cn = 0; cn < 4; cn++)
                acc[rm][cn] = __builtin_amdgcn_mfma_f32_16x16x32_bf16(af[rm], bfr[cn], acc[rm][cn], 0, 0, 0);
    }

    // ---- epilogue: h = relu(acc + b1); partial s = h . W2 ----
    float b1v[4], w2v[4];
#pragma unroll
    for (int cn = 0; cn < 4; cn++) {
        int col = wave * 64 + cn * 16 + l15;
        b1v[cn] = b1[col];
        w2v[cn] = W2[col];
    }
#pragma unroll
    for (int rm = 0; rm < 4; rm++) {
#pragma unroll
        for (int r = 0; r < 4; r++) {
            float p = 0.f;
#pragma unroll
            for (int cn = 0; cn < 4; cn++) {
                float h = acc[rm][cn][r] + b1v[cn];
                h = h > 0.f ? h : 0.f;
                p += h * w2v[cn];
            }
            p += __shfl_xor(p, 1);
            p += __shfl_xor(p, 2);
            p += __shfl_xor(p, 4);
            p += __shfl_xor(p, 8);
            if (l15 == 0) sS[wave][rm * 16 + quad * 4 + r] = p;
        }
    }
    __syncthreads();

    if (t < 64) {
        float x = sS[0][t] + sS[1][t] + sS[2][t] + sS[3][t] + b2[0];
        float s = 1.0f / (1.0f + __expf(-x));
        int src = sSrc[t];
        int dst = sDst[t];
        out[((size_t)b * N_ + src) * N_ + dst] = s;
    }
}

extern "C" void kernel_launch(void* const* d_in, const int* in_sizes, int n_in,
                              void* d_out, int out_size, void* d_ws, size_t ws_size,
                              hipStream_t stream) {
    const float* feat = (const float*)d_in[0];
    const float* W1   = (const float*)d_in[1];
    const float* b1   = (const float*)d_in[2];
    const float* W2   = (const float*)d_in[3];
    const float* b2   = (const float*)d_in[4];
    const int*   eidx = (const int*)d_in[5];
    float* out = (float*)d_out;
    unsigned short* W1T = (unsigned short*)d_ws;   // 256 KB

    int n4 = out_size / 4;                          // 524288 float4s
    zero_out_k<<<(n4 + 255) / 256, 256, 0, stream>>>((float4*)out, n4);
    conv_w1t_k<<<512, 256, 0, stream>>>(W1, W1T);
    fused_edge_mlp<<<(B_ * E_) / 64, 256, 0, stream>>>(feat, W1T, b1, W2, b2, eidx, out);
}

// Round 2
// 106.906 us; speedup vs baseline: 1.4022x; 1.4022x over previous
//
#include <hip/hip_runtime.h>
#include <hip/hip_bf16.h>
#include <cstdint>

#define B_ 8
#define N_ 512
#define D_ 256
#define E_ 16384
#define H_ 256

#define SA_STRIDE 56
#define SB_STRIDE 56
#define ZB 2048   // zero-fill blocks in prep kernel

using bf16x8 = __attribute__((ext_vector_type(8))) short;
using f32x4  = __attribute__((ext_vector_type(4))) float;

__device__ inline unsigned short f2bf(float f) {
    union { float f; unsigned u; } v; v.f = f;
    unsigned u = v.u;
    return (unsigned short)((u + 0x7fffu + ((u >> 16) & 1u)) >> 16);  // RNE
}

// blocks [0,ZB): zero d_out.  blocks [ZB, ZB+32): transpose W1 halves ->
// BT (512 n-rows x 256 k) bf16, BT[n,k] = W1[k + (n>=256)*256, n&255]
__global__ __launch_bounds__(256)
void prep_k(const float* __restrict__ W1, float4* __restrict__ out4,
            unsigned short* __restrict__ W1T) {
    __shared__ float tile[64][65];
    const int bx = blockIdx.x, t = threadIdx.x;
    if (bx < ZB) {
        out4[(size_t)bx * 256 + t] = make_float4(0.f, 0.f, 0.f, 0.f);
        return;
    }
    const int tb  = bx - ZB;            // 0..31
    const int h   = tb >> 4;            // half of W1
    const int rem = tb & 15;
    const int tk  = (rem >> 2) * 64;
    const int tn  = (rem & 3) * 64;
    const float* Wh = W1 + (size_t)h * 256 * 256;
    const int c = t & 63, r0 = t >> 6;
#pragma unroll
    for (int i = 0; i < 16; i++) {
        int r = r0 + i * 4;
        tile[r][c] = Wh[(size_t)(tk + r) * 256 + tn + c];
    }
    __syncthreads();
#pragma unroll
    for (int i = 0; i < 16; i++) {
        int rn = r0 + i * 4;
        W1T[(size_t)(h * 256 + tn + rn) * 256 + tk + c] = f2bf(tile[c][rn]);
    }
}

// P (4096,512) fp32 = feat(4096,256) x [W1a | W1b](256,512); cols 0-255 = U, 256-511 = V
__global__ __launch_bounds__(256)
void node_gemm(const float* __restrict__ feat,
               const unsigned short* __restrict__ W1T,
               float* __restrict__ P) {
    __shared__ unsigned short sA[64 * SA_STRIDE];
    __shared__ unsigned short sB[256 * SB_STRIDE];

    const int t  = threadIdx.x;
    const int bm = blockIdx.x >> 1;
    const int bn = blockIdx.x & 1;
    const int m0 = bm * 64;

    const int arow = t >> 2;
    const int akg  = (t & 3) * 8;
    const float* pA = feat + (size_t)(m0 + arow) * 256;
    const unsigned short* pB = W1T + (size_t)(bn * 256 + t) * 256;

    const int wave = t >> 6, lane = t & 63, l15 = lane & 15, quad = lane >> 4;

    f32x4 acc[4][4];
#pragma unroll
    for (int rm = 0; rm < 4; rm++)
#pragma unroll
        for (int cn = 0; cn < 4; cn++)
            acc[rm][cn] = (f32x4){0.f, 0.f, 0.f, 0.f};

    for (int k0 = 0; k0 < 256; k0 += 32) {
        __syncthreads();
        {
            float4 lo = *(const float4*)(pA + k0 + akg);
            float4 hi = *(const float4*)(pA + k0 + akg + 4);
            union { bf16x8 v; unsigned short s[8]; } u;
            u.s[0] = f2bf(lo.x); u.s[1] = f2bf(lo.y); u.s[2] = f2bf(lo.z); u.s[3] = f2bf(lo.w);
            u.s[4] = f2bf(hi.x); u.s[5] = f2bf(hi.y); u.s[6] = f2bf(hi.z); u.s[7] = f2bf(hi.w);
            *(bf16x8*)(sA + arow * SA_STRIDE + akg) = u.v;
        }
        {
            const unsigned short* p = pB + k0;
            uint4 q0 = *(const uint4*)(p);
            uint4 q1 = *(const uint4*)(p + 8);
            uint4 q2 = *(const uint4*)(p + 16);
            uint4 q3 = *(const uint4*)(p + 24);
            *(uint4*)(sB + t * SB_STRIDE +  0) = q0;
            *(uint4*)(sB + t * SB_STRIDE +  8) = q1;
            *(uint4*)(sB + t * SB_STRIDE + 16) = q2;
            *(uint4*)(sB + t * SB_STRIDE + 24) = q3;
        }
        __syncthreads();

        bf16x8 af[4], bfr[4];
#pragma unroll
        for (int rm = 0; rm < 4; rm++)
            af[rm] = *(const bf16x8*)(sA + (rm * 16 + l15) * SA_STRIDE + quad * 8);
#pragma unroll
        for (int cn = 0; cn < 4; cn++)
            bfr[cn] = *(const bf16x8*)(sB + (wave * 64 + cn * 16 + l15) * SB_STRIDE + quad * 8);
#pragma unroll
        for (int rm = 0; rm < 4; rm++)
#pragma unroll
            for (int cn = 0; cn < 4; cn++)
                acc[rm][cn] = __builtin_amdgcn_mfma_f32_16x16x32_bf16(af[rm], bfr[cn], acc[rm][cn], 0, 0, 0);
    }

#pragma unroll
    for (int rm = 0; rm < 4; rm++)
#pragma unroll
        for (int cn = 0; cn < 4; cn++) {
            int col = bn * 256 + wave * 64 + cn * 16 + l15;
#pragma unroll
            for (int r = 0; r < 4; r++) {
                int row = m0 + rm * 16 + quad * 4 + r;
                P[(size_t)row * 512 + col] = acc[rm][cn][r];
            }
        }
}

// per-edge: s = sigmoid(relu(U[src]+V[dst]+b1) . W2 + b2), scatter to out
__global__ __launch_bounds__(256)
void edge_score(const float* __restrict__ P,
                const float* __restrict__ b1, const float* __restrict__ W2,
                const float* __restrict__ b2, const int* __restrict__ eidx,
                float* __restrict__ out) {
    const int wid  = blockIdx.x * 4 + (threadIdx.x >> 6);
    const int lane = threadIdx.x & 63;
    const int g0   = wid * 16;          // 16 edges per wave, same batch
    const int b    = g0 >> 14;
    const int e0   = g0 & (E_ - 1);

    const float4 b1v = *(const float4*)(b1 + lane * 4);
    const float4 w2v = *(const float4*)(W2 + lane * 4);
    const float  b2v = b2[0];

    const float* Pb   = P   + (size_t)b * 512 * 512;
    float*       outb = out + (size_t)b * 512 * 512;

    int my_e = 0;
    if (lane < 16)      my_e = eidx[e0 + lane];
    else if (lane < 32) my_e = eidx[E_ + e0 + (lane - 16)];

#pragma unroll 4
    for (int i = 0; i < 16; i++) {
        int src = __shfl(my_e, i);
        int dst = __shfl(my_e, 16 + i);
        float4 u = *(const float4*)(Pb + (size_t)src * 512 + lane * 4);
        float4 v = *(const float4*)(Pb + (size_t)dst * 512 + 256 + lane * 4);
        float hx = fmaxf(u.x + v.x + b1v.x, 0.f);
        float hy = fmaxf(u.y + v.y + b1v.y, 0.f);
        float hz = fmaxf(u.z + v.z + b1v.z, 0.f);
        float hw = fmaxf(u.w + v.w + b1v.w, 0.f);
        float p = hx * w2v.x + hy * w2v.y + hz * w2v.z + hw * w2v.w;
        p += __shfl_xor(p, 1);
        p += __shfl_xor(p, 2);
        p += __shfl_xor(p, 4);
        p += __shfl_xor(p, 8);
        p += __shfl_xor(p, 16);
        p += __shfl_xor(p, 32);
        if (lane == 0) {
            float s = 1.0f / (1.0f + __expf(-(p + b2v)));
            outb[(size_t)src * 512 + dst] = s;
        }
    }
}

extern "C" void kernel_launch(void* const* d_in, const int* in_sizes, int n_in,
                              void* d_out, int out_size, void* d_ws, size_t ws_size,
                              hipStream_t stream) {
    const float* feat = (const float*)d_in[0];
    const float* W1   = (const float*)d_in[1];
    const float* b1   = (const float*)d_in[2];
    const float* W2   = (const float*)d_in[3];
    const float* b2   = (const float*)d_in[4];
    const int*   eidx = (const int*)d_in[5];
    float* out = (float*)d_out;

    unsigned short* W1T = (unsigned short*)d_ws;                  // 256 KB
    float* P = (float*)((char*)d_ws + (1 << 20));                 // 8 MB

    prep_k<<<ZB + 32, 256, 0, stream>>>(W1, (float4*)out, W1T);
    node_gemm<<<128, 256, 0, stream>>>(feat, W1T, P);
    edge_score<<<2048, 256, 0, stream>>>(P, b1, W2, b2, eidx, out);
}

// Round 3
// 96.546 us; speedup vs baseline: 1.5527x; 1.1073x over previous
//
#include <hip/hip_runtime.h>
#include <hip/hip_bf16.h>
#include <cstdint>

#define B_ 8
#define N_ 512
#define D_ 256
#define E_ 16384
#define H_ 256

#define SA_STRIDE 56
#define SB_STRIDE 56
#define ZB 2048   // zero-fill blocks in prep kernel

using bf16x8 = __attribute__((ext_vector_type(8))) short;
using f32x4  = __attribute__((ext_vector_type(4))) float;

__device__ inline unsigned short f2bf(float f) {
    union { float f; unsigned u; } v; v.f = f;
    unsigned u = v.u;
    return (unsigned short)((u + 0x7fffu + ((u >> 16) & 1u)) >> 16);  // RNE
}

__device__ inline float bf2f(unsigned short s) {
    union { unsigned u; float f; } v; v.u = ((unsigned)s) << 16;
    return v.f;
}

// blocks [0,ZB): zero d_out.  blocks [ZB, ZB+32): transpose W1 halves ->
// W1T (512 n-rows x 256 k) bf16, W1T[n,k] = W1[k + (n>=256)*256, n&255]
__global__ __launch_bounds__(256)
void prep_k(const float* __restrict__ W1, float4* __restrict__ out4,
            unsigned short* __restrict__ W1T) {
    __shared__ float tile[64][65];
    const int bx = blockIdx.x, t = threadIdx.x;
    if (bx < ZB) {
        out4[(size_t)bx * 256 + t] = make_float4(0.f, 0.f, 0.f, 0.f);
        return;
    }
    const int tb  = bx - ZB;            // 0..31
    const int h   = tb >> 4;            // half of W1
    const int rem = tb & 15;
    const int tk  = (rem >> 2) * 64;
    const int tn  = (rem & 3) * 64;
    const float* Wh = W1 + (size_t)h * 256 * 256;
    const int c = t & 63, r0 = t >> 6;
#pragma unroll
    for (int i = 0; i < 16; i++) {
        int r = r0 + i * 4;
        tile[r][c] = Wh[(size_t)(tk + r) * 256 + tn + c];
    }
    __syncthreads();
#pragma unroll
    for (int i = 0; i < 16; i++) {
        int rn = r0 + i * 4;
        W1T[(size_t)(h * 256 + tn + rn) * 256 + tk + c] = f2bf(tile[c][rn]);
    }
}

// P (4096,512) bf16 = feat(4096,256) x [W1a | W1b](256,512); cols 0-255 = U, 256-511 = V
__global__ __launch_bounds__(256)
void node_gemm(const float* __restrict__ feat,
               const unsigned short* __restrict__ W1T,
               unsigned short* __restrict__ P) {
    __shared__ unsigned short sA[64 * SA_STRIDE];
    __shared__ unsigned short sB[256 * SB_STRIDE];

    const int t  = threadIdx.x;
    const int bm = blockIdx.x >> 1;
    const int bn = blockIdx.x & 1;
    const int m0 = bm * 64;

    const int arow = t >> 2;
    const int akg  = (t & 3) * 8;
    const float* pA = feat + (size_t)(m0 + arow) * 256;
    const unsigned short* pB = W1T + (size_t)(bn * 256 + t) * 256;

    const int wave = t >> 6, lane = t & 63, l15 = lane & 15, quad = lane >> 4;

    f32x4 acc[4][4];
#pragma unroll
    for (int rm = 0; rm < 4; rm++)
#pragma unroll
        for (int cn = 0; cn < 4; cn++)
            acc[rm][cn] = (f32x4){0.f, 0.f, 0.f, 0.f};

    for (int k0 = 0; k0 < 256; k0 += 32) {
        __syncthreads();
        {
            float4 lo = *(const float4*)(pA + k0 + akg);
            float4 hi = *(const float4*)(pA + k0 + akg + 4);
            union { bf16x8 v; unsigned short s[8]; } u;
            u.s[0] = f2bf(lo.x); u.s[1] = f2bf(lo.y); u.s[2] = f2bf(lo.z); u.s[3] = f2bf(lo.w);
            u.s[4] = f2bf(hi.x); u.s[5] = f2bf(hi.y); u.s[6] = f2bf(hi.z); u.s[7] = f2bf(hi.w);
            *(bf16x8*)(sA + arow * SA_STRIDE + akg) = u.v;
        }
        {
            const unsigned short* p = pB + k0;
            uint4 q0 = *(const uint4*)(p);
            uint4 q1 = *(const uint4*)(p + 8);
            uint4 q2 = *(const uint4*)(p + 16);
            uint4 q3 = *(const uint4*)(p + 24);
            *(uint4*)(sB + t * SB_STRIDE +  0) = q0;
            *(uint4*)(sB + t * SB_STRIDE +  8) = q1;
            *(uint4*)(sB + t * SB_STRIDE + 16) = q2;
            *(uint4*)(sB + t * SB_STRIDE + 24) = q3;
        }
        __syncthreads();

        bf16x8 af[4], bfr[4];
#pragma unroll
        for (int rm = 0; rm < 4; rm++)
            af[rm] = *(const bf16x8*)(sA + (rm * 16 + l15) * SA_STRIDE + quad * 8);
#pragma unroll
        for (int cn = 0; cn < 4; cn++)
            bfr[cn] = *(const bf16x8*)(sB + (wave * 64 + cn * 16 + l15) * SB_STRIDE + quad * 8);
#pragma unroll
        for (int rm = 0; rm < 4; rm++)
#pragma unroll
            for (int cn = 0; cn < 4; cn++)
                acc[rm][cn] = __builtin_amdgcn_mfma_f32_16x16x32_bf16(af[rm], bfr[cn], acc[rm][cn], 0, 0, 0);
    }

#pragma unroll
    for (int rm = 0; rm < 4; rm++)
#pragma unroll
        for (int cn = 0; cn < 4; cn++) {
            int col = bn * 256 + wave * 64 + cn * 16 + l15;
#pragma unroll
            for (int r = 0; r < 4; r++) {
                int row = m0 + rm * 16 + quad * 4 + r;
                P[(size_t)row * 512 + col] = f2bf(acc[rm][cn][r]);
            }
        }
}

// per-edge: s = sigmoid(relu(U[src]+V[dst]+b1) . W2 + b2), scatter to out.
// XCD-aware: batch = blockIdx & 7 so each XCD's blocks touch one 512 KB P-slice.
__global__ __launch_bounds__(256)
void edge_score(const unsigned short* __restrict__ P,
                const float* __restrict__ b1, const float* __restrict__ W2,
                const float* __restrict__ b2, const int* __restrict__ eidx,
                float* __restrict__ out) {
    const int b    = blockIdx.x & 7;
    const int blk  = blockIdx.x >> 3;           // 0..255 within batch
    const int wave = threadIdx.x >> 6;
    const int lane = threadIdx.x & 63;
    const int e0   = (blk * 4 + wave) * 16;     // 16 edges per wave

    const float4 b1v = *(const float4*)(b1 + lane * 4);
    const float4 w2v = *(const float4*)(W2 + lane * 4);
    const float  b2v = b2[0];

    const unsigned short* Pb = P + (size_t)b * 512 * 512;
    float*               outb = out + (size_t)b * 512 * 512;

    int my_e = 0;
    if (lane < 16)      my_e = eidx[e0 + lane];
    else if (lane < 32) my_e = eidx[E_ + e0 + (lane - 16)];

#pragma unroll 4
    for (int i = 0; i < 16; i++) {
        int src = __shfl(my_e, i);
        int dst = __shfl(my_e, 16 + i);
        ushort4 ua = *(const ushort4*)(Pb + (size_t)src * 512 + lane * 4);
        ushort4 va = *(const ushort4*)(Pb + (size_t)dst * 512 + 256 + lane * 4);
        float hx = fmaxf(bf2f(ua.x) + bf2f(va.x) + b1v.x, 0.f);
        float hy = fmaxf(bf2f(ua.y) + bf2f(va.y) + b1v.y, 0.f);
        float hz = fmaxf(bf2f(ua.z) + bf2f(va.z) + b1v.z, 0.f);
        float hw = fmaxf(bf2f(ua.w) + bf2f(va.w) + b1v.w, 0.f);
        float p = hx * w2v.x + hy * w2v.y + hz * w2v.z + hw * w2v.w;
        p += __shfl_xor(p, 1);
        p += __shfl_xor(p, 2);
        p += __shfl_xor(p, 4);
        p += __shfl_xor(p, 8);
        p += __shfl_xor(p, 16);
        p += __shfl_xor(p, 32);
        if (lane == 0) {
            float s = 1.0f / (1.0f + __expf(-(p + b2v)));
            outb[(size_t)src * 512 + dst] = s;
        }
    }
}

extern "C" void kernel_launch(void* const* d_in, const int* in_sizes, int n_in,
                              void* d_out, int out_size, void* d_ws, size_t ws_size,
                              hipStream_t stream) {
    const float* feat = (const float*)d_in[0];
    const float* W1   = (const float*)d_in[1];
    const float* b1   = (const float*)d_in[2];
    const float* W2   = (const float*)d_in[3];
    const float* b2   = (const float*)d_in[4];
    const int*   eidx = (const int*)d_in[5];
    float* out = (float*)d_out;

    unsigned short* W1T = (unsigned short*)d_ws;                  // 256 KB
    unsigned short* P   = (unsigned short*)((char*)d_ws + (1 << 20));  // 4 MB bf16

    prep_k<<<ZB + 32, 256, 0, stream>>>(W1, (float4*)out, W1T);
    node_gemm<<<128, 256, 0, stream>>>(feat, W1T, P);
    edge_score<<<2048, 256, 0, stream>>>(P, b1, W2, b2, eidx, out);
}

// Round 4
// 92.818 us; speedup vs baseline: 1.6151x; 1.0402x over previous
//
#include <hip/hip_runtime.h>
#include <hip/hip_bf16.h>
#include <cstdint>

#define B_ 8
#define N_ 512
#define D_ 256
#define E_ 16384
#define H_ 256

#define SA_STRIDE 56
#define SB_STRIDE 56

using bf16x8 = __attribute__((ext_vector_type(8))) short;
using f32x4  = __attribute__((ext_vector_type(4))) float;

__device__ inline unsigned short f2bf(float f) {
    union { float f; unsigned u; } v; v.f = f;
    unsigned u = v.u;
    return (unsigned short)((u + 0x7fffu + ((u >> 16) & 1u)) >> 16);  // RNE
}

// 32 blocks: transpose W1 halves -> W1T (512 n-rows x 256 k) bf16,
// W1T[n,k] = W1[k + (n>=256)*256, n&255]
__global__ __launch_bounds__(256)
void prep_k(const float* __restrict__ W1, unsigned short* __restrict__ W1T) {
    __shared__ float tile[64][65];
    const int tb = blockIdx.x, t = threadIdx.x;
    const int h   = tb >> 4;
    const int rem = tb & 15;
    const int tk  = (rem >> 2) * 64;
    const int tn  = (rem & 3) * 64;
    const float* Wh = W1 + (size_t)h * 256 * 256;
    const int c = t & 63, r0 = t >> 6;
#pragma unroll
    for (int i = 0; i < 16; i++) {
        int r = r0 + i * 4;
        tile[r][c] = Wh[(size_t)(tk + r) * 256 + tn + c];
    }
    __syncthreads();
#pragma unroll
    for (int i = 0; i < 16; i++) {
        int rn = r0 + i * 4;
        W1T[(size_t)(h * 256 + tn + rn) * 256 + tk + c] = f2bf(tile[c][rn]);
    }
}

// P (4096,512) bf16 = feat(4096,256) x [W1a | W1b](256,512).
// Also zeroes d_out (each of 128 blocks clears 64 KB) — memory pipe is idle here.
__global__ __launch_bounds__(256)
void node_gemm(const float* __restrict__ feat,
               const unsigned short* __restrict__ W1T,
               unsigned short* __restrict__ P,
               float4* __restrict__ out4) {
    __shared__ unsigned short sA[64 * SA_STRIDE];
    __shared__ unsigned short sB[256 * SB_STRIDE];

    const int t  = threadIdx.x;
    const int bm = blockIdx.x >> 1;
    const int bn = blockIdx.x & 1;
    const int m0 = bm * 64;

    // zero 64 KB of out: 4096 float4 per block
    {
        float4 z = make_float4(0.f, 0.f, 0.f, 0.f);
        float4* oz = out4 + (size_t)blockIdx.x * 4096 + t;
#pragma unroll
        for (int i = 0; i < 16; i++) oz[i * 256] = z;
    }

    const int arow = t >> 2;
    const int akg  = (t & 3) * 8;
    const float* pA = feat + (size_t)(m0 + arow) * 256;
    const unsigned short* pB = W1T + (size_t)(bn * 256 + t) * 256;

    const int wave = t >> 6, lane = t & 63, l15 = lane & 15, quad = lane >> 4;

    f32x4 acc[4][4];
#pragma unroll
    for (int rm = 0; rm < 4; rm++)
#pragma unroll
        for (int cn = 0; cn < 4; cn++)
            acc[rm][cn] = (f32x4){0.f, 0.f, 0.f, 0.f};

    for (int k0 = 0; k0 < 256; k0 += 32) {
        __syncthreads();
        {
            float4 lo = *(const float4*)(pA + k0 + akg);
            float4 hi = *(const float4*)(pA + k0 + akg + 4);
            union { bf16x8 v; unsigned short s[8]; } u;
            u.s[0] = f2bf(lo.x); u.s[1] = f2bf(lo.y); u.s[2] = f2bf(lo.z); u.s[3] = f2bf(lo.w);
            u.s[4] = f2bf(hi.x); u.s[5] = f2bf(hi.y); u.s[6] = f2bf(hi.z); u.s[7] = f2bf(hi.w);
            *(bf16x8*)(sA + arow * SA_STRIDE + akg) = u.v;
        }
        {
            const unsigned short* p = pB + k0;
            uint4 q0 = *(const uint4*)(p);
            uint4 q1 = *(const uint4*)(p + 8);
            uint4 q2 = *(const uint4*)(p + 16);
            uint4 q3 = *(const uint4*)(p + 24);
            *(uint4*)(sB + t * SB_STRIDE +  0) = q0;
            *(uint4*)(sB + t * SB_STRIDE +  8) = q1;
            *(uint4*)(sB + t * SB_STRIDE + 16) = q2;
            *(uint4*)(sB + t * SB_STRIDE + 24) = q3;
        }
        __syncthreads();

        bf16x8 af[4], bfr[4];
#pragma unroll
        for (int rm = 0; rm < 4; rm++)
            af[rm] = *(const bf16x8*)(sA + (rm * 16 + l15) * SA_STRIDE + quad * 8);
#pragma unroll
        for (int cn = 0; cn < 4; cn++)
            bfr[cn] = *(const bf16x8*)(sB + (wave * 64 + cn * 16 + l15) * SB_STRIDE + quad * 8);
#pragma unroll
        for (int rm = 0; rm < 4; rm++)
#pragma unroll
            for (int cn = 0; cn < 4; cn++)
                acc[rm][cn] = __builtin_amdgcn_mfma_f32_16x16x32_bf16(af[rm], bfr[cn], acc[rm][cn], 0, 0, 0);
    }

#pragma unroll
    for (int rm = 0; rm < 4; rm++)
#pragma unroll
        for (int cn = 0; cn < 4; cn++) {
            int col = bn * 256 + wave * 64 + cn * 16 + l15;
#pragma unroll
            for (int r = 0; r < 4; r++) {
                int row = m0 + rm * 16 + quad * 4 + r;
                P[(size_t)row * 512 + col] = f2bf(acc[rm][cn][r]);
            }
        }
}

// 8 bf16 pairs (qu,qv) -> partial relu-dot with b1/W2 slices
__device__ inline float dot8(uint4 qu, uint4 qv, const float* b1p, const float* w2p) {
    unsigned us[4] = {qu.x, qu.y, qu.z, qu.w};
    unsigned vs[4] = {qv.x, qv.y, qv.z, qv.w};
    float p = 0.f;
#pragma unroll
    for (int j = 0; j < 4; j++) {
        float ulo = __uint_as_float(us[j] << 16);
        float uhi = __uint_as_float(us[j] & 0xffff0000u);
        float vlo = __uint_as_float(vs[j] << 16);
        float vhi = __uint_as_float(vs[j] & 0xffff0000u);
        float hlo = fmaxf(ulo + vlo + b1p[2 * j],     0.f);
        float hhi = fmaxf(uhi + vhi + b1p[2 * j + 1], 0.f);
        p = fmaf(hlo, w2p[2 * j],     p);
        p = fmaf(hhi, w2p[2 * j + 1], p);
    }
    return p;
}

// per-edge: s = sigmoid(relu(U[src]+V[dst]+b1) . W2 + b2), scatter to out.
// 4 edges concurrently per wave, 16 lanes/edge (lane covers 16 h-cols).
__global__ __launch_bounds__(256)
void edge_score(const unsigned short* __restrict__ P,
                const float* __restrict__ b1, const float* __restrict__ W2,
                const float* __restrict__ b2, const int* __restrict__ eidx,
                float* __restrict__ out) {
    const int b    = blockIdx.x & 7;           // XCD-aware: one batch per XCD
    const int blk  = blockIdx.x >> 3;
    const int wave = threadIdx.x >> 6;
    const int lane = threadIdx.x & 63;
    const int g    = lane >> 4;                // edge-slot group 0..3
    const int w    = lane & 15;                // lane-in-group
    const int e0   = (blk * 4 + wave) * 16;    // 16 edges per wave

    float b1r[16], w2r[16];
#pragma unroll
    for (int j = 0; j < 4; j++) {
        *(float4*)(b1r + 4 * j) = *(const float4*)(b1 + w * 16 + 4 * j);
        *(float4*)(w2r + 4 * j) = *(const float4*)(W2 + w * 16 + 4 * j);
    }
    const float b2v = b2[0];

    const unsigned short* Pb = P + (size_t)b * 512 * 512;
    float* outb = out + (size_t)b * 512 * 512;

    int my_e = 0;
    if (lane < 16)      my_e = eidx[e0 + lane];
    else if (lane < 32) my_e = eidx[E_ + e0 + (lane - 16)];

#pragma unroll
    for (int i = 0; i < 4; i++) {
        int eid = i * 4 + g;
        int src = __shfl(my_e, eid);
        int dst = __shfl(my_e, 16 + eid);
        const unsigned short* pu = Pb + (size_t)src * 512 + w * 16;
        const unsigned short* pv = Pb + (size_t)dst * 512 + 256 + w * 16;
        uint4 u0 = *(const uint4*)(pu);
        uint4 u1 = *(const uint4*)(pu + 8);
        uint4 v0 = *(const uint4*)(pv);
        uint4 v1 = *(const uint4*)(pv + 8);
        float p = dot8(u0, v0, b1r, w2r) + dot8(u1, v1, b1r + 8, w2r + 8);
        p += __shfl_xor(p, 1);
        p += __shfl_xor(p, 2);
        p += __shfl_xor(p, 4);
        p += __shfl_xor(p, 8);
        if (w == 0) {
            float s = 1.0f / (1.0f + __expf(-(p + b2v)));
            outb[(size_t)src * 512 + dst] = s;
        }
    }
}

extern "C" void kernel_launch(void* const* d_in, const int* in_sizes, int n_in,
                              void* d_out, int out_size, void* d_ws, size_t ws_size,
                              hipStream_t stream) {
    const float* feat = (const float*)d_in[0];
    const float* W1   = (const float*)d_in[1];
    const float* b1   = (const float*)d_in[2];
    const float* W2   = (const float*)d_in[3];
    const float* b2   = (const float*)d_in[4];
    const int*   eidx = (const int*)d_in[5];
    float* out = (float*)d_out;

    unsigned short* W1T = (unsigned short*)d_ws;                       // 512 KB
    unsigned short* P   = (unsigned short*)((char*)d_ws + (1 << 20));  // 4 MB bf16

    prep_k<<<32, 256, 0, stream>>>(W1, W1T);
    node_gemm<<<128, 256, 0, stream>>>(feat, W1T, P, (float4*)out);
    edge_score<<<2048, 256, 0, stream>>>(P, b1, W2, b2, eidx, out);
}